// Round 1
// baseline (82.032 us; speedup 1.0000x reference)
//
#include <hip/hip_runtime.h>
#include <hip/hip_bf16.h>

#define BATCH   1024
#define IN_DIM  128
#define OUT_DIM 256
#define NUM_F   8

// Block tile: 32 batches x 32 outputs, K = IN_DIM*NUM_F + IN_DIM = 1152
#define BM 32
#define BN 32
#define BK 32
#define NCHUNK 36      // 32 sin-chunks (k=1024) + 4 silu-chunks (k=128)

#define XPAD 129       // x_lds row stride (floats) — breaks power-of-2 conflicts
#define APAD 40        // A/B LDS row stride in bf16 (80 B: 16B-aligned, odd word-pairs)

typedef __attribute__((ext_vector_type(8))) short short8;   // 8 bf16 = 4 VGPRs (MFMA A/B frag)
typedef __attribute__((ext_vector_type(4))) float float4v;  // MFMA C/D frag

static __device__ __forceinline__ unsigned short f2bf(float f) {
    union { float f; unsigned u; } v; v.f = f;
    unsigned r = v.u + 0x7FFFu + ((v.u >> 16) & 1u);   // round-to-nearest-even
    return (unsigned short)(r >> 16);
}

__global__ __launch_bounds__(256)
void slayer_kernel(const float* __restrict__ x,
                   const float* __restrict__ coef,
                   const float* __restrict__ scale_sp,
                   const float* __restrict__ scale_base,
                   const float* __restrict__ bias_w,
                   float* __restrict__ y)
{
    __shared__ float x_lds[BM * XPAD];
    __shared__ short A_lds[BM * APAD];
    __shared__ short B_lds[BN * APAD];

    const int t  = threadIdx.x;
    const int o0 = blockIdx.x * BN;
    const int b0 = blockIdx.y * BM;

    // ---- stage x tile [32][128] (fully coalesced float4 loads) ----
    {
        const float4v* xg = (const float4v*)(x + b0 * IN_DIM);
        #pragma unroll
        for (int r = 0; r < 4; ++r) {
            int flat = r * 1024 + t * 4;          // float index within tile
            int b = flat >> 7, i = flat & 127;
            float4v v = xg[r * 256 + t];
            x_lds[b * XPAD + i + 0] = v.x;
            x_lds[b * XPAD + i + 1] = v.y;
            x_lds[b * XPAD + i + 2] = v.z;
            x_lds[b * XPAD + i + 3] = v.w;
        }
    }
    __syncthreads();

    const int wave = t >> 6;
    const int lane = t & 63;
    const int mrow = lane & 15;        // row of A-frag / col of B-frag / col of C
    const int q    = lane >> 4;        // quad
    const int mw   = (wave & 1) * 16;  // wave's m offset within 32x32 tile
    const int nw   = (wave >> 1) * 16; // wave's n offset

    float4v acc = {0.f, 0.f, 0.f, 0.f};

    for (int c = 0; c < NCHUNK; ++c) {
        if (c < 32) {
            // k-chunk covers i in [c*4, c*4+4), f in [0,8)
            const int i0 = c * 4;
            if (t < 128) {
                // A: sin basis via Chebyshev recurrence s_{n+1} = 2cos(x) s_n - s_{n-1}
                int b = t >> 2, il = t & 3;
                float xv = x_lds[b * XPAD + i0 + il];
                float s1 = __sinf(xv), c1 = __cosf(xv);
                float c2 = 2.f * c1;
                float s2 = c2 * s1;
                float s3 = c2 * s2 - s1;
                float s4 = c2 * s3 - s2;
                float s5 = c2 * s4 - s3;
                float s6 = c2 * s5 - s4;
                float s7 = c2 * s6 - s5;
                float s8 = c2 * s7 - s6;
                short8 pk;
                pk[0] = f2bf(s1); pk[1] = f2bf(s2); pk[2] = f2bf(s3); pk[3] = f2bf(s4);
                pk[4] = f2bf(s5); pk[5] = f2bf(s6); pk[6] = f2bf(s7); pk[7] = f2bf(s8);
                *(short8*)&A_lds[b * APAD + il * 8] = pk;
            } else {
                // B: coef[n,0..7] * scale_sp[n], n = (o0+o)*128 + i0 + il
                int t2 = t - 128;
                int o = t2 >> 2, il = t2 & 3;
                int n = (o0 + o) * IN_DIM + i0 + il;
                float sp = scale_sp[n];
                const float4v* cg = (const float4v*)(coef + (size_t)n * NUM_F);
                float4v v0 = cg[0], v1 = cg[1];
                short8 pk;
                pk[0] = f2bf(v0.x * sp); pk[1] = f2bf(v0.y * sp);
                pk[2] = f2bf(v0.z * sp); pk[3] = f2bf(v0.w * sp);
                pk[4] = f2bf(v1.x * sp); pk[5] = f2bf(v1.y * sp);
                pk[6] = f2bf(v1.z * sp); pk[7] = f2bf(v1.w * sp);
                *(short8*)&B_lds[o * APAD + il * 8] = pk;
            }
        } else {
            // silu tail: k-chunk covers i in [(c-32)*32, +32)
            const int i0 = (c - 32) * 32;
            if (t < 128) {
                int b = t >> 2, kk = (t & 3) * 8;
                short8 pk;
                #pragma unroll
                for (int j = 0; j < 8; ++j) {
                    float xv = x_lds[b * XPAD + i0 + kk + j];
                    float s  = xv / (1.f + __expf(-xv));
                    pk[j] = f2bf(s);
                }
                *(short8*)&A_lds[b * APAD + kk] = pk;
            } else {
                int t2 = t - 128;
                int o = t2 >> 2, kk = (t2 & 3) * 8;
                const float* sb = scale_base + (size_t)(o0 + o) * IN_DIM + i0 + kk;
                short8 pk;
                #pragma unroll
                for (int j = 0; j < 8; ++j) pk[j] = f2bf(sb[j]);
                *(short8*)&B_lds[o * APAD + kk] = pk;
            }
        }
        __syncthreads();

        // A-frag: A[m = mw+mrow][k = q*8 + j] ; B-frag: B[k = q*8 + j][n = nw+mrow]
        short8 af = *(const short8*)&A_lds[(mw + mrow) * APAD + q * 8];
        short8 bf = *(const short8*)&B_lds[(nw + mrow) * APAD + q * 8];
        acc = __builtin_amdgcn_mfma_f32_16x16x32_bf16(af, bf, acc, 0, 0, 0);

        __syncthreads();   // protect LDS before next chunk overwrites
    }

    // ---- epilogue: C/D layout col = lane&15, row = q*4 + reg ----
    const int ocol = o0 + nw + mrow;
    const float bias = bias_w[ocol];
    #pragma unroll
    for (int r = 0; r < 4; ++r) {
        int brow = b0 + mw + q * 4 + r;
        y[(size_t)brow * OUT_DIM + ocol] = acc[r] + bias;
    }
}

extern "C" void kernel_launch(void* const* d_in, const int* in_sizes, int n_in,
                              void* d_out, int out_size, void* d_ws, size_t ws_size,
                              hipStream_t stream) {
    const float* x          = (const float*)d_in[0];
    // d_in[1] = grid (arange+1) — folded into the sin recurrence
    const float* coef       = (const float*)d_in[2];
    const float* scale_sp   = (const float*)d_in[3];
    const float* scale_base = (const float*)d_in[4];
    const float* bias_w     = (const float*)d_in[5];
    float* y = (float*)d_out;

    dim3 grid(OUT_DIM / BN, BATCH / BM);   // 8 x 32 = 256 blocks
    slayer_kernel<<<grid, 256, 0, stream>>>(x, coef, scale_sp, scale_base, bias_w, y);
}

// Round 2
// 76.003 us; speedup vs baseline: 1.0793x; 1.0793x over previous
//
#include <hip/hip_runtime.h>
#include <hip/hip_bf16.h>

#define IN_DIM  128
#define OUT_DIM 256
#define NUM_F   8
#define BATCH   1024

#define BM 32          // batch tile
#define BN 32          // output tile
#define XPAD 132       // x_lds row stride (floats), mult of 4 -> 16B-aligned rows

typedef __attribute__((ext_vector_type(8))) short short8;   // MFMA A/B frag (8 bf16)
typedef __attribute__((ext_vector_type(4))) float float4v;  // MFMA C/D frag / vec loads

static __device__ __forceinline__ unsigned pk2(float a, float b) {
    float2 t; t.x = a; t.y = b;
    __hip_bfloat162 h = __float22bfloat162_rn(t);   // packed RNE cvt (v_cvt_pk_bf16_f32)
    union { __hip_bfloat162 h; unsigned u; } v; v.h = h;
    return v.u;
}

__global__ __launch_bounds__(256)
void slayer_kernel(const float* __restrict__ x,
                   const float* __restrict__ coef,
                   const float* __restrict__ scale_sp,
                   const float* __restrict__ scale_base,
                   const float* __restrict__ bias_w,
                   float* __restrict__ y)
{
    __shared__ float x_lds[BM * XPAD];

    const int t  = threadIdx.x;
    const int o0 = blockIdx.x * BN;   // gridDim.x = 8 -> XCD-affine o-slices
    const int b0 = blockIdx.y * BM;

    // ---- stage x tile [32][128], coalesced float4 ----
    {
        const float4v* xg = (const float4v*)(x + (size_t)b0 * IN_DIM);
        #pragma unroll
        for (int r = 0; r < 4; ++r) {
            int idx = r * 256 + t;            // float4 index, 0..1023
            int b = idx >> 5, i4 = idx & 31;  // 32 float4 per row
            float4v v = xg[idx];
            *(float4v*)&x_lds[b * XPAD + i4 * 4] = v;
        }
    }
    __syncthreads();   // the only barrier

    const int wave = t >> 6, lane = t & 63;
    const int mrow = lane & 15, q = lane >> 4;
    const int mw = (wave & 1) * 16, nw = (wave >> 1) * 16;
    const int m  = mw + mrow;                 // batch row within tile
    const int nn = o0 + nw + mrow;            // global output col

    const float* xrow = &x_lds[m * XPAD];     // 2-way bank alias at most (free)

    float4v acc = {0.f, 0.f, 0.f, 0.f};

    // ---- sin chunks: k = (i - i0)*8 + f inside chunk; i = c*4 + q, f = j ----
    #pragma unroll 4
    for (int c = 0; c < 32; ++c) {
        const int i = c * 4 + q;
        const size_t nidx = (size_t)nn * IN_DIM + i;

        // B frag: coef[nidx][0..7] * scale_sp[nidx]  (8 contiguous floats)
        const float4v* cg = (const float4v*)(coef + nidx * NUM_F);
        float4v c0 = cg[0], c1 = cg[1];
        float sp = scale_sp[nidx];

        // A frag: sin((j+1)*x) via Chebyshev recurrence, straight into regs
        float xv = xrow[i];
        float s1 = __sinf(xv), cs = __cosf(xv);
        float c2 = cs + cs;
        float s2 = c2 * s1;
        float s3 = c2 * s2 - s1;
        float s4 = c2 * s3 - s2;
        float s5 = c2 * s4 - s3;
        float s6 = c2 * s5 - s4;
        float s7 = c2 * s6 - s5;
        float s8 = c2 * s7 - s6;

        union { short8 s; unsigned u[4]; } af, bf;
        af.u[0] = pk2(s1, s2); af.u[1] = pk2(s3, s4);
        af.u[2] = pk2(s5, s6); af.u[3] = pk2(s7, s8);
        bf.u[0] = pk2(c0.x * sp, c0.y * sp); bf.u[1] = pk2(c0.z * sp, c0.w * sp);
        bf.u[2] = pk2(c1.x * sp, c1.y * sp); bf.u[3] = pk2(c1.z * sp, c1.w * sp);

        acc = __builtin_amdgcn_mfma_f32_16x16x32_bf16(af.s, bf.s, acc, 0, 0, 0);
    }

    // ---- silu tail: 4 chunks, k inside chunk = q*8 + j <-> i = c*32 + q*8 + j ----
    #pragma unroll
    for (int c = 0; c < 4; ++c) {
        const int i0 = c * 32 + q * 8;
        float4v xa = *(const float4v*)&xrow[i0];
        float4v xb = *(const float4v*)&xrow[i0 + 4];
        const float4v* sb = (const float4v*)(scale_base + (size_t)nn * IN_DIM + i0);
        float4v g0 = sb[0], g1 = sb[1];

        float s[8] = {xa.x, xa.y, xa.z, xa.w, xb.x, xb.y, xb.z, xb.w};
        #pragma unroll
        for (int j = 0; j < 8; ++j) s[j] = s[j] / (1.f + __expf(-s[j]));

        union { short8 s; unsigned u[4]; } af, bf;
        af.u[0] = pk2(s[0], s[1]); af.u[1] = pk2(s[2], s[3]);
        af.u[2] = pk2(s[4], s[5]); af.u[3] = pk2(s[6], s[7]);
        bf.u[0] = pk2(g0.x, g0.y); bf.u[1] = pk2(g0.z, g0.w);
        bf.u[2] = pk2(g1.x, g1.y); bf.u[3] = pk2(g1.z, g1.w);

        acc = __builtin_amdgcn_mfma_f32_16x16x32_bf16(af.s, bf.s, acc, 0, 0, 0);
    }

    // ---- epilogue: C/D layout col = lane&15 (n), row = q*4 + reg (m) ----
    const float bias = bias_w[nn];
    #pragma unroll
    for (int r = 0; r < 4; ++r) {
        int brow = b0 + mw + q * 4 + r;
        y[(size_t)brow * OUT_DIM + nn] = acc[r] + bias;
    }
}

extern "C" void kernel_launch(void* const* d_in, const int* in_sizes, int n_in,
                              void* d_out, int out_size, void* d_ws, size_t ws_size,
                              hipStream_t stream) {
    const float* x          = (const float*)d_in[0];
    // d_in[1] = grid (arange+1) — folded into the sin recurrence
    const float* coef       = (const float*)d_in[2];
    const float* scale_sp   = (const float*)d_in[3];
    const float* scale_base = (const float*)d_in[4];
    const float* bias_w     = (const float*)d_in[5];
    float* y = (float*)d_out;

    dim3 grid(OUT_DIM / BN, BATCH / BM);   // 8 x 32 = 256 blocks, x = o-block (XCD affinity)
    slayer_kernel<<<grid, 256, 0, stream>>>(x, coef, scale_sp, scale_base, bias_w, y);
}

// Round 3
// 75.196 us; speedup vs baseline: 1.0909x; 1.0107x over previous
//
#include <hip/hip_runtime.h>
#include <hip/hip_bf16.h>

#define IN_DIM  128
#define OUT_DIM 256
#define NUM_F   8
#define BATCH   1024

#define BM 16          // batch tile
#define BN 16          // output tile
#define XPAD 132       // x_lds row stride (floats): %32==4 -> 2-way bank alias max (free)

typedef __attribute__((ext_vector_type(8))) short short8;   // MFMA A/B frag (8 bf16)
typedef __attribute__((ext_vector_type(4))) float float4v;  // MFMA C/D frag / vec loads

static __device__ __forceinline__ unsigned pk2(float a, float b) {
    float2 t; t.x = a; t.y = b;
    __hip_bfloat162 h = __float22bfloat162_rn(t);   // v_cvt_pk_bf16_f32
    union { __hip_bfloat162 h; unsigned u; } v; v.h = h;
    return v.u;
}

__global__ __launch_bounds__(256, 4)   // 4 waves/EU -> 4 blocks/CU, 16 waves/CU
void slayer_kernel(const float* __restrict__ x,
                   const float* __restrict__ coef,
                   const float* __restrict__ scale_sp,
                   const float* __restrict__ scale_base,
                   const float* __restrict__ bias_w,
                   float* __restrict__ y)
{
    __shared__ float   x_lds[BM * XPAD];   // 8.25 KB
    __shared__ float4v red[3][64];         // 3 KB cross-wave reduction

    const int t  = threadIdx.x;
    const int o0 = blockIdx.x * BN;   // gridDim.x = 16 -> o-slice x lands on XCD x%8
    const int b0 = blockIdx.y * BM;

    // ---- stage x tile [16][128], coalesced float4 ----
    {
        const float4v* xg = (const float4v*)(x + (size_t)b0 * IN_DIM);
        #pragma unroll
        for (int r = 0; r < 2; ++r) {
            int idx = r * 256 + t;            // float4 index 0..511
            int b = idx >> 5, i4 = idx & 31;
            float4v v = xg[idx];
            *(float4v*)&x_lds[b * XPAD + i4 * 4] = v;
        }
    }
    __syncthreads();

    const int wave = t >> 6, lane = t & 63;
    const int mrow = lane & 15, q = lane >> 4;
    const int m  = mrow;                  // batch row within tile
    const int nn = o0 + mrow;             // global output col

    const float* xrow = &x_lds[m * XPAD];

    float4v acc = {0.f, 0.f, 0.f, 0.f};

    // ---- K-split: wave w owns sin chunks c = w + 4*cc (cc=0..7) + silu chunk w ----
    #pragma unroll 4
    for (int cc = 0; cc < 8; ++cc) {
        const int c = wave + 4 * cc;
        const int i = c * 4 + q;
        const size_t nidx = (size_t)nn * IN_DIM + i;

        // B frag: coef[nidx][0..7] * scale_sp[nidx]
        const float4v* cg = (const float4v*)(coef + nidx * NUM_F);
        float4v c0 = cg[0], c1 = cg[1];
        float sp = scale_sp[nidx];

        // A frag: sin((j+1)*x) Chebyshev recurrence in-register
        float xv = xrow[i];
        float s1 = __sinf(xv), cs = __cosf(xv);
        float c2 = cs + cs;
        float s2 = c2 * s1;
        float s3 = c2 * s2 - s1;
        float s4 = c2 * s3 - s2;
        float s5 = c2 * s4 - s3;
        float s6 = c2 * s5 - s4;
        float s7 = c2 * s6 - s5;
        float s8 = c2 * s7 - s6;

        union { short8 s; unsigned u[4]; } af, bf;
        af.u[0] = pk2(s1, s2); af.u[1] = pk2(s3, s4);
        af.u[2] = pk2(s5, s6); af.u[3] = pk2(s7, s8);
        bf.u[0] = pk2(c0.x * sp, c0.y * sp); bf.u[1] = pk2(c0.z * sp, c0.w * sp);
        bf.u[2] = pk2(c1.x * sp, c1.y * sp); bf.u[3] = pk2(c1.z * sp, c1.w * sp);

        acc = __builtin_amdgcn_mfma_f32_16x16x32_bf16(af.s, bf.s, acc, 0, 0, 0);
    }

    // ---- silu chunk `wave`: i = wave*32 + q*8 + j ----
    {
        const int i0 = wave * 32 + q * 8;
        float4v xa = *(const float4v*)&xrow[i0];
        float4v xb = *(const float4v*)&xrow[i0 + 4];
        const float4v* sb = (const float4v*)(scale_base + (size_t)nn * IN_DIM + i0);
        float4v g0 = sb[0], g1 = sb[1];

        float s[8] = {xa.x, xa.y, xa.z, xa.w, xb.x, xb.y, xb.z, xb.w};
        #pragma unroll
        for (int j = 0; j < 8; ++j) s[j] = s[j] / (1.f + __expf(-s[j]));

        union { short8 s; unsigned u[4]; } af, bf;
        af.u[0] = pk2(s[0], s[1]); af.u[1] = pk2(s[2], s[3]);
        af.u[2] = pk2(s[4], s[5]); af.u[3] = pk2(s[6], s[7]);
        bf.u[0] = pk2(g0.x, g0.y); bf.u[1] = pk2(g0.z, g0.w);
        bf.u[2] = pk2(g1.x, g1.y); bf.u[3] = pk2(g1.z, g1.w);

        acc = __builtin_amdgcn_mfma_f32_16x16x32_bf16(af.s, bf.s, acc, 0, 0, 0);
    }

    // ---- cross-wave K reduction ----
    if (wave > 0) red[wave - 1][lane] = acc;
    __syncthreads();
    if (wave == 0) {
        float4v r0 = red[0][lane], r1 = red[1][lane], r2 = red[2][lane];
        acc.x += r0.x + r1.x + r2.x;
        acc.y += r0.y + r1.y + r2.y;
        acc.z += r0.z + r1.z + r2.z;
        acc.w += r0.w + r1.w + r2.w;

        // C/D layout: col = lane&15 (n), row = q*4 + reg (m)
        const float bias = bias_w[nn];
        #pragma unroll
        for (int r = 0; r < 4; ++r) {
            int brow = b0 + q * 4 + r;
            y[(size_t)brow * OUT_DIM + nn] = acc[r] + bias;
        }
    }
}

extern "C" void kernel_launch(void* const* d_in, const int* in_sizes, int n_in,
                              void* d_out, int out_size, void* d_ws, size_t ws_size,
                              hipStream_t stream) {
    const float* x          = (const float*)d_in[0];
    // d_in[1] = grid (arange+1) — folded into the sin recurrence
    const float* coef       = (const float*)d_in[2];
    const float* scale_sp   = (const float*)d_in[3];
    const float* scale_base = (const float*)d_in[4];
    const float* bias_w     = (const float*)d_in[5];
    float* y = (float*)d_out;

    dim3 grid(OUT_DIM / BN, BATCH / BM);   // 16 x 64 = 1024 blocks -> 4 blocks/CU
    slayer_kernel<<<grid, 256, 0, stream>>>(x, coef, scale_sp, scale_base, bias_w, y);
}